// Round 1
// baseline (657.143 us; speedup 1.0000x reference)
//
#include <hip/hip_runtime.h>
#include <math.h>

#define HDIM 128  // feature dim (32 float4)

// ---------------------------------------------------------------------------
// Kernel 1: segment boundaries. batch is sorted, so starts[b] = first index i
// with batch[i] >= b. Each thread i writes starts[b] for all b in
// (batch[i-1], batch[i]]; thread 0 covers [0, batch[0]]; last thread covers
// (batch[n-1], B]. Every starts[0..B] entry is written exactly once per call
// (d_ws is re-poisoned before every timed launch, so we must rewrite it).
// ---------------------------------------------------------------------------
__global__ void seg_bounds_kernel(const int* __restrict__ batch, int n, int nseg,
                                  int* __restrict__ starts) {
    int i = blockIdx.x * blockDim.x + threadIdx.x;
    if (i >= n) return;
    int cur  = batch[i];
    int prev = (i == 0) ? -1 : batch[i - 1];
    for (int b = prev + 1; b <= cur; ++b) starts[b] = i;
    if (i == n - 1) {
        for (int b = cur + 1; b <= nseg; ++b) starts[b] = n;
    }
}

// ---------------------------------------------------------------------------
// Kernel 2: one block per segment. 256 threads = 32 float4-columns x 8
// row-parallel groups. Consecutive 32 lanes read one whole 512B row
// (coalesced float4). Register accumulation over rows (stride 8), then a
// small LDS tree-reduce across the 8 row groups, then 32 lanes store
// sum / mean / max as float4 into out[b, 0:384].
// ---------------------------------------------------------------------------
__global__ __launch_bounds__(256) void seg_agg_kernel(
        const float* __restrict__ x, const int* __restrict__ starts,
        float* __restrict__ out) {
    const int b   = blockIdx.x;
    const int tid = threadIdx.x;
    const int c   = tid & 31;   // float4 column 0..31
    const int rp  = tid >> 5;   // row-parallel group 0..7

    const int s = starts[b];
    const int e = starts[b + 1];

    float4 sum = make_float4(0.f, 0.f, 0.f, 0.f);
    float4 mx  = make_float4(-INFINITY, -INFINITY, -INFINITY, -INFINITY);

    for (int r = s + rp; r < e; r += 8) {
        const float4 v = *reinterpret_cast<const float4*>(
            x + (size_t)r * HDIM + (c << 2));
        sum.x += v.x; sum.y += v.y; sum.z += v.z; sum.w += v.w;
        mx.x = fmaxf(mx.x, v.x); mx.y = fmaxf(mx.y, v.y);
        mx.z = fmaxf(mx.z, v.z); mx.w = fmaxf(mx.w, v.w);
    }

    __shared__ float4 ssum[8][32];
    __shared__ float4 smax[8][32];
    ssum[rp][c] = sum;
    smax[rp][c] = mx;
    __syncthreads();

    #pragma unroll
    for (int off = 4; off >= 1; off >>= 1) {
        if (rp < off) {
            float4 a  = ssum[rp][c];
            float4 bb = ssum[rp + off][c];
            a.x += bb.x; a.y += bb.y; a.z += bb.z; a.w += bb.w;
            ssum[rp][c] = a;
            float4 m  = smax[rp][c];
            float4 mm = smax[rp + off][c];
            m.x = fmaxf(m.x, mm.x); m.y = fmaxf(m.y, mm.y);
            m.z = fmaxf(m.z, mm.z); m.w = fmaxf(m.w, mm.w);
            smax[rp][c] = m;
        }
        __syncthreads();
    }

    if (rp == 0) {
        const int cnt = e - s;
        float4 s4 = ssum[0][c];
        float4 m4 = smax[0][c];
        const float denom = (float)(cnt > 0 ? cnt : 1);
        float4 mean4;
        mean4.x = s4.x / denom; mean4.y = s4.y / denom;
        mean4.z = s4.z / denom; mean4.w = s4.w / denom;
        if (cnt <= 0) {
            s4 = make_float4(0.f, 0.f, 0.f, 0.f);
            mean4 = s4;
            m4 = s4;
        }
        float4* ob = reinterpret_cast<float4*>(out + (size_t)b * (3 * HDIM));
        ob[c]      = s4;     // seg_sum  -> cols [0,128)
        ob[32 + c] = mean4;  // seg_mean -> cols [128,256)
        ob[64 + c] = m4;     // seg_max  -> cols [256,384)
    }
}

extern "C" void kernel_launch(void* const* d_in, const int* in_sizes, int n_in,
                              void* d_out, int out_size, void* d_ws, size_t ws_size,
                              hipStream_t stream) {
    const float* x     = (const float*)d_in[0];
    const int*   batch = (const int*)d_in[1];
    // d_in[2] is the batch_size scalar on device; derive B from out_size
    // (out = [B, 3*H]) so we never need a host readback.
    const int n = in_sizes[1];               // N rows
    const int B = out_size / (3 * HDIM);     // 4096 segments

    int* starts = (int*)d_ws;                // (B+1) ints, 16 KB of scratch

    float* out = (float*)d_out;

    seg_bounds_kernel<<<(n + 255) / 256, 256, 0, stream>>>(batch, n, B, starts);
    seg_agg_kernel<<<B, 256, 0, stream>>>(x, starts, out);
}

// Round 4
// 624.116 us; speedup vs baseline: 1.0529x; 1.0529x over previous
//
#include <hip/hip_runtime.h>
#include <math.h>

#define HDIM 128   // feature dim (32 float4 per row)

// clang-native vector type — required by __builtin_nontemporal_load
// (HIP's float4 is a class and is rejected by the builtin).
typedef float f4 __attribute__((ext_vector_type(4)));

// ---------------------------------------------------------------------------
// Kernel 1: segment boundaries. batch is sorted, so starts[b] = first index i
// with batch[i] >= b. Each thread i writes starts[b] for all b in
// (batch[i-1], batch[i]]; thread 0 covers [0, batch[0]]; last thread covers
// (batch[n-1], B]. Every starts[0..B] entry is rewritten each call since d_ws
// is re-poisoned before every timed launch.
// ---------------------------------------------------------------------------
__global__ void seg_bounds_kernel(const int* __restrict__ batch, int n, int nseg,
                                  int* __restrict__ starts) {
    int i = blockIdx.x * blockDim.x + threadIdx.x;
    if (i >= n) return;
    int cur  = batch[i];
    int prev = (i == 0) ? -1 : batch[i - 1];
    for (int b = prev + 1; b <= cur; ++b) starts[b] = i;
    if (i == n - 1) {
        for (int b = cur + 1; b <= nseg; ++b) starts[b] = n;
    }
}

// ---------------------------------------------------------------------------
// Kernel 2: one block per segment. 256 threads = 32 float4-columns x 8
// row-parallel groups; 32 consecutive lanes read one full 512B row (so a
// wave64 reads 1KB contiguous). Manual 4x unroll keeps 4 independent loads
// in flight per wave (MLP), two accumulator chains cut dependency latency,
// nontemporal loads avoid cache pollution (x is streamed once, no reuse).
// ---------------------------------------------------------------------------
__global__ __launch_bounds__(256) void seg_agg_kernel(
        const float* __restrict__ x, const int* __restrict__ starts,
        float* __restrict__ out) {
    const int b   = blockIdx.x;
    const int tid = threadIdx.x;
    const int c   = tid & 31;   // float4 column 0..31
    const int rp  = tid >> 5;   // row-parallel group 0..7

    const int s = starts[b];
    const int e = starts[b + 1];

    const f4* xc = reinterpret_cast<const f4*>(x) + c;  // col base

    f4 sum0 = (f4)(0.f);
    f4 sum1 = (f4)(0.f);
    f4 mx0  = (f4)(-INFINITY);
    f4 mx1  = (f4)(-INFINITY);

    int r = s + rp;
    // main loop: 4 rows per thread per iteration (stride 8 between rows)
    for (; r + 24 < e; r += 32) {
        const f4 v0 = __builtin_nontemporal_load(xc + (size_t)(r)      * 32);
        const f4 v1 = __builtin_nontemporal_load(xc + (size_t)(r + 8)  * 32);
        const f4 v2 = __builtin_nontemporal_load(xc + (size_t)(r + 16) * 32);
        const f4 v3 = __builtin_nontemporal_load(xc + (size_t)(r + 24) * 32);
        sum0 += v0; sum1 += v1; sum0 += v2; sum1 += v3;
        mx0.x = fmaxf(mx0.x, v0.x); mx0.y = fmaxf(mx0.y, v0.y);
        mx0.z = fmaxf(mx0.z, v0.z); mx0.w = fmaxf(mx0.w, v0.w);
        mx1.x = fmaxf(mx1.x, v1.x); mx1.y = fmaxf(mx1.y, v1.y);
        mx1.z = fmaxf(mx1.z, v1.z); mx1.w = fmaxf(mx1.w, v1.w);
        mx0.x = fmaxf(mx0.x, v2.x); mx0.y = fmaxf(mx0.y, v2.y);
        mx0.z = fmaxf(mx0.z, v2.z); mx0.w = fmaxf(mx0.w, v2.w);
        mx1.x = fmaxf(mx1.x, v3.x); mx1.y = fmaxf(mx1.y, v3.y);
        mx1.z = fmaxf(mx1.z, v3.z); mx1.w = fmaxf(mx1.w, v3.w);
    }
    // tail
    for (; r < e; r += 8) {
        const f4 v = __builtin_nontemporal_load(xc + (size_t)r * 32);
        sum0 += v;
        mx0.x = fmaxf(mx0.x, v.x); mx0.y = fmaxf(mx0.y, v.y);
        mx0.z = fmaxf(mx0.z, v.z); mx0.w = fmaxf(mx0.w, v.w);
    }
    // merge the two chains
    sum0 += sum1;
    mx0.x = fmaxf(mx0.x, mx1.x); mx0.y = fmaxf(mx0.y, mx1.y);
    mx0.z = fmaxf(mx0.z, mx1.z); mx0.w = fmaxf(mx0.w, mx1.w);

    __shared__ f4 ssum[8][32];
    __shared__ f4 smax[8][32];
    ssum[rp][c] = sum0;
    smax[rp][c] = mx0;
    __syncthreads();

    #pragma unroll
    for (int off = 4; off >= 1; off >>= 1) {
        if (rp < off) {
            f4 a  = ssum[rp][c];
            f4 bb = ssum[rp + off][c];
            a += bb;
            ssum[rp][c] = a;
            f4 m  = smax[rp][c];
            f4 mm = smax[rp + off][c];
            m.x = fmaxf(m.x, mm.x); m.y = fmaxf(m.y, mm.y);
            m.z = fmaxf(m.z, mm.z); m.w = fmaxf(m.w, mm.w);
            smax[rp][c] = m;
        }
        __syncthreads();
    }

    if (rp == 0) {
        const int cnt = e - s;
        f4 s4 = ssum[0][c];
        f4 m4 = smax[0][c];
        const float denom = (float)(cnt > 0 ? cnt : 1);
        f4 mean4 = s4 / denom;
        if (cnt <= 0) {
            s4 = (f4)(0.f);
            mean4 = (f4)(0.f);
            m4 = (f4)(0.f);
        }
        f4* ob = reinterpret_cast<f4*>(out + (size_t)b * (3 * HDIM));
        ob[c]      = s4;     // seg_sum  -> cols [0,128)
        ob[32 + c] = mean4;  // seg_mean -> cols [128,256)
        ob[64 + c] = m4;     // seg_max  -> cols [256,384)
    }
}

extern "C" void kernel_launch(void* const* d_in, const int* in_sizes, int n_in,
                              void* d_out, int out_size, void* d_ws, size_t ws_size,
                              hipStream_t stream) {
    const float* x     = (const float*)d_in[0];
    const int*   batch = (const int*)d_in[1];
    const int n = in_sizes[1];               // N rows
    const int B = out_size / (3 * HDIM);     // 4096 segments

    int* starts = (int*)d_ws;                // (B+1) ints of scratch
    float* out = (float*)d_out;

    seg_bounds_kernel<<<(n + 255) / 256, 256, 0, stream>>>(batch, n, B, starts);
    seg_agg_kernel<<<B, 256, 0, stream>>>(x, starts, out);
}